// Round 4
// baseline (999.626 us; speedup 1.0000x reference)
//
#include <hip/hip_runtime.h>

#define NC    1000000
#define NPAR  100000
#define DIM   64
#define H     4
#define RPE   9
#define SCALE 0.35355339059327373f  // DQK^-0.5
#define CB    128                   // children per fused tile
#define NBS   ((NPAR + 1023) / 1024)  // 98 scan blocks
#define NT_TILES ((NC + CB - 1) / CB) // 7813
#define GRID_F 1024                   // 4 blocks/CU exactly (reg-capped at 16 waves/CU)

typedef __attribute__((ext_vector_type(8))) short short8;   // 8 bf16 (4 VGPRs)
typedef __attribute__((ext_vector_type(4))) float f32x4;    // MFMA C/D frag

__device__ inline unsigned short f2bf(float f) {
    unsigned int u = __float_as_uint(f);
    u += 0x7fff + ((u >> 16) & 1);          // round-to-nearest-even
    return (unsigned short)(u >> 16);
}
__device__ inline unsigned int pack2bf(float a, float b) {
    return (unsigned int)f2bf(a) | ((unsigned int)f2bf(b) << 16);
}

// ---------------------------------------------------------------------------
// Kernel A: qp[p][o] = SCALE*(x_parent[p].wq[:,o] + bq[o]). Thread per parent.
// ---------------------------------------------------------------------------
__global__ __launch_bounds__(256) void qproj_kernel(const float* __restrict__ xp,
                             const float* __restrict__ wq,
                             const float* __restrict__ bq,
                             float* __restrict__ qp) {
    __shared__ float wqT[32 * 64];   // wqT[o*64+j] = wq[j*32+o]
    __shared__ float bqL[32];
    int tid = threadIdx.x;
    for (int i = tid; i < 2048; i += 256) { int o = i >> 6, j = i & 63; wqT[i] = wq[j * 32 + o]; }
    if (tid < 32) bqL[tid] = bq[tid];
    __syncthreads();
    int p = blockIdx.x * 256 + tid;
    if (p >= NPAR) return;
    float4 x4[16];
    const float4* xr = (const float4*)(xp + (size_t)p * 64);
#pragma unroll
    for (int i = 0; i < 16; ++i) x4[i] = xr[i];
    float* qpr = qp + (size_t)p * 32;
#pragma unroll 1
    for (int o = 0; o < 32; ++o) {
        float acc = bqL[o];
        const float4* w4 = (const float4*)(wqT + o * 64);
#pragma unroll
        for (int j = 0; j < 16; ++j) { float4 w = w4[j], xx = x4[j];
            acc += xx.x * w.x + xx.y * w.y + xx.z * w.z + xx.w * w.w; }
        qpr[o] = acc * SCALE;
    }
}

// ---------------------------------------------------------------------------
// Kernel P: pre-pack B (96x128 bf16 GEMM operand) into global, once.
// ---------------------------------------------------------------------------
__global__ __launch_bounds__(256) void prepB_kernel(
    const float* __restrict__ wkv, const float* __restrict__ bkv,
    const float* __restrict__ wkr, const float* __restrict__ bkr,
    const float* __restrict__ wqr, const float* __restrict__ bqr,
    uint4* __restrict__ Bg) {
    int tid = threadIdx.x;
    for (int i = tid; i < 12 * 128; i += 256) {
        int kb = i >> 7, n = i & 127;
        float w[8];
#pragma unroll
        for (int jj = 0; jj < 8; ++jj) {
            int k = kb * 8 + jj;
            float val = 0.f;
            if (n < 32) {                       // k-projection (x + rpe + bias)
                if (k < 64)       val = wkv[k * 96 + n];
                else if (k < 73)  val = wkr[(k - 64) * 32 + n];
                else if (k == 73) val = bkv[n] + bkr[n];
            } else if (n < 96) {                // v-projection
                int d = n - 32;
                if (k < 64)       val = wkv[k * 96 + 32 + d];
                else if (k == 73) val = bkv[32 + d];
            } else {                            // q rpe (+bias)
                int o = n - 96;
                if (k >= 64 && k < 73) val = wqr[(k - 64) * 32 + o];
                else if (k == 73)      val = bqr[o];
            }
            w[jj] = val;
        }
        uint4 v;
        v.x = pack2bf(w[0], w[1]); v.y = pack2bf(w[2], w[3]);
        v.z = pack2bf(w[4], w[5]); v.w = pack2bf(w[6], w[7]);
        Bg[kb * 128 + n] = v;
    }
}

// ---------------------------------------------------------------------------
// Kernel B1: per-parent child histogram (1M int atomics).
// ---------------------------------------------------------------------------
__global__ __launch_bounds__(256) void hist_kernel(const int* __restrict__ index,
                            int* __restrict__ cnt) {
    int c = blockIdx.x * 256 + threadIdx.x;
    if (c >= NC) return;
    atomicAdd(&cnt[index[c]], 1);
}

// ---------------------------------------------------------------------------
// Scan phase A: per-block sums of cnt (98 blocks x 1024 threads).
// ---------------------------------------------------------------------------
__global__ __launch_bounds__(1024) void scanA_kernel(const int* __restrict__ cnt,
                                                     int* __restrict__ bsum) {
    __shared__ int red[16];
    int i = blockIdx.x * 1024 + threadIdx.x;
    int v = (i < NPAR) ? cnt[i] : 0;
#pragma unroll
    for (int off = 32; off; off >>= 1) v += __shfl_down(v, off, 64);
    if ((threadIdx.x & 63) == 0) red[threadIdx.x >> 6] = v;
    __syncthreads();
    if (threadIdx.x < 16) {
        int s = red[threadIdx.x];
#pragma unroll
        for (int off = 8; off; off >>= 1) s += __shfl_down(s, off, 16);
        if (threadIdx.x == 0) bsum[blockIdx.x] = s;
    }
}

// ---------------------------------------------------------------------------
// Scan phase B: exclusive scan of the 98 block sums (1 tiny block).
// ---------------------------------------------------------------------------
__global__ __launch_bounds__(128) void scanB_kernel(int* __restrict__ bsum) {
    __shared__ int s[128];
    int t = threadIdx.x;
    int v = (t < NBS) ? bsum[t] : 0;
    s[t] = v;
    __syncthreads();
    for (int off = 1; off < 128; off <<= 1) {
        int x = s[t];
        int add = (t >= off) ? s[t - off] : 0;
        __syncthreads();
        s[t] = x + add;
        __syncthreads();
    }
    if (t < NBS) bsum[t] = s[t] - v;    // inclusive -> exclusive
}

// ---------------------------------------------------------------------------
// Scan phase C: block-local exclusive scan + block offset -> rowStart, cursor.
// ---------------------------------------------------------------------------
__global__ __launch_bounds__(1024) void scanC_kernel(const int* __restrict__ cnt,
                                                     const int* __restrict__ bsum,
                                                     int* __restrict__ rowStart,
                                                     int* __restrict__ cursor) {
    __shared__ int s[1024];
    int t = threadIdx.x;
    int i = blockIdx.x * 1024 + t;
    int v = (i < NPAR) ? cnt[i] : 0;
    s[t] = v;
    __syncthreads();
    for (int off = 1; off < 1024; off <<= 1) {
        int x = s[t];
        int add = (t >= off) ? s[t - off] : 0;
        __syncthreads();
        s[t] = x + add;
        __syncthreads();
    }
    int excl = s[t] - v + bsum[blockIdx.x];
    if (i < NPAR) { rowStart[i] = excl; cursor[i] = excl; }
    if (i == NPAR - 1) rowStart[NPAR] = excl + v;
}

// ---------------------------------------------------------------------------
// Kernel B3: scatter via cursor atomics: ordCP[cursor[p]++] = (c, p)
// ---------------------------------------------------------------------------
__global__ __launch_bounds__(256) void scatter_kernel(const int* __restrict__ index,
                               int* __restrict__ cursor,
                               int2* __restrict__ ordCP) {
    int c = blockIdx.x * 256 + threadIdx.x;
    if (c >= NC) return;
    int p = index[c];
    int pos = atomicAdd(&cursor[p], 1);
    ordCP[pos] = make_int2(c, p);
}

// ---------------------------------------------------------------------------
// Kernel C: MFMA fused pass, persistent blocks + 1-tile register prefetch.
//  grid = 1024 (4 blocks/CU); each block loops over ~8 tiles of 128 children.
//  Per iter: write staged regs->LDS, MFMA, issue next gather, in-reg compat
//  (mt-sequential, 8-float comp, reg-budget <=128), pack, scale-v, reduce.
// ---------------------------------------------------------------------------
__global__ __launch_bounds__(256, 4) void fused_kernel(
    const float* __restrict__ xc, const float* __restrict__ ea_g,
    const int2* __restrict__ ordCP,
    const int* __restrict__ rowStart,
    const uint4* __restrict__ Bg,
    const float* __restrict__ qp,
    float* __restrict__ outw, float* __restrict__ sW)
{
    __shared__ __align__(16) char R1[34816];   // A(20.5K) -> wvS(34816) aliased
    __shared__ float e_lds[CB * 4];
    __shared__ int par_s[CB];
    __shared__ int wcnt[4];
    __shared__ int segStart[130];              // [<=128]=starts+cap, [129]=nseg

    uint4* A4 = (uint4*)R1;                    // A4[kb*128 + c], kb=0..9
    float* wvS = (float*)R1;                   // [128][68] f32, e-scaled v

    const int tid  = threadIdx.x;
    const int lane = tid & 63, wave = tid >> 6;
    const int col  = lane & 15, quad = lane >> 4;
    const int c    = tid & 127;
    const int half = tid >> 7;                 // waves 0,1 = half0; 2,3 = half1
    const int wbase = wave * 32;
    const short8 zero8 = {0, 0, 0, 0, 0, 0, 0, 0};

    int t = blockIdx.x;
    int2 cp;       // (child,parent) of staged tile
    uint4 pk[5];   // packed bf16 A-rows of staged tile (this thread's share)

    // ---- prologue: stage tile t into registers ----
    {
        int g = t * CB + c;
        bool v = g < NC;
        int2 cl = ordCP[v ? g : 0];
        if (!v) { cl.x = 0; cl.y = 0x7fffffff; }
        int ch = cl.x;
        float4 xa[10]; float ear[9];
        if (half == 0) {
            const float4* xr = (const float4*)(xc + (size_t)ch * 64);
#pragma unroll
            for (int i = 0; i < 10; ++i) xa[i] = xr[i];
#pragma unroll
            for (int kb = 0; kb < 5; ++kb) {
                uint4 u;
                u.x = pack2bf(xa[kb*2].x,   xa[kb*2].y);
                u.y = pack2bf(xa[kb*2].z,   xa[kb*2].w);
                u.z = pack2bf(xa[kb*2+1].x, xa[kb*2+1].y);
                u.w = pack2bf(xa[kb*2+1].z, xa[kb*2+1].w);
                pk[kb] = v ? u : make_uint4(0u,0u,0u,0u);
            }
        } else {
            const float4* xr = (const float4*)(xc + (size_t)ch * 64);
#pragma unroll
            for (int i = 0; i < 6; ++i) xa[i] = xr[10 + i];
            const float* er = ea_g + (size_t)ch * 9;
#pragma unroll
            for (int r = 0; r < 9; ++r) ear[r] = er[r];
#pragma unroll
            for (int kb = 0; kb < 3; ++kb) {
                uint4 u;
                u.x = pack2bf(xa[kb*2].x,   xa[kb*2].y);
                u.y = pack2bf(xa[kb*2].z,   xa[kb*2].w);
                u.z = pack2bf(xa[kb*2+1].x, xa[kb*2+1].y);
                u.w = pack2bf(xa[kb*2+1].z, xa[kb*2+1].w);
                pk[kb] = v ? u : make_uint4(0u,0u,0u,0u);
            }
            uint4 u8;
            u8.x = pack2bf(ear[0], ear[1]); u8.y = pack2bf(ear[2], ear[3]);
            u8.z = pack2bf(ear[4], ear[5]); u8.w = pack2bf(ear[6], ear[7]);
            pk[3] = v ? u8 : make_uint4(0u,0u,0u,0u);
            uint4 u9;
            u9.x = pack2bf(ear[8], 1.f); u9.y = 0u; u9.z = 0u; u9.w = 0u;
            pk[4] = v ? u9 : make_uint4(0u,0u,0u,0u);
        }
        cp = cl;
    }

    for (; t < NT_TILES; t += GRID_F) {
        const int G = t * CB;
        const int validCB = min(NC - G, CB);

        // ---- issue next tile's ordCP early (lands during MFMA) ----
        int tn = (t + GRID_F < NT_TILES) ? (t + GRID_F) : t;  // clamp: L2-hot reload
        int gn = tn * CB + c;
        bool vn = gn < NC;
        int2 cpn = ordCP[vn ? gn : 0];

        // ---- write staged regs -> LDS ----
        if (half == 0) {
            par_s[c] = cp.y;
#pragma unroll
            for (int kb = 0; kb < 5; ++kb) A4[kb * 128 + c] = pk[kb];
        } else {
#pragma unroll
            for (int kb = 0; kb < 5; ++kb) A4[(5 + kb) * 128 + c] = pk[kb];
        }
        __syncthreads();   // B1: A4/par_s ready

        // ---- P2: MFMA. Wave computes 32 children x 128 outputs ----
        f32x4 acc[2][8];
#pragma unroll
        for (int mt = 0; mt < 2; ++mt)
#pragma unroll
            for (int nt = 0; nt < 8; ++nt) acc[mt][nt] = (f32x4){0.f, 0.f, 0.f, 0.f};
        const short8* As = (const short8*)A4;
        const short8* Bs = (const short8*)Bg;
#pragma unroll
        for (int ks = 0; ks < 3; ++ks) {
            const int kb = ks * 4 + quad;
            short8 af0 = zero8, af1 = zero8;
            if (kb < 10) {
                af0 = As[kb * 128 + wbase + col];
                af1 = As[kb * 128 + wbase + 16 + col];
            }
            short8 bf[4];
#pragma unroll
            for (int nt = 0; nt < 4; ++nt) bf[nt] = Bs[kb * 128 + nt * 16 + col];
#pragma unroll
            for (int nt = 0; nt < 4; ++nt) {
                acc[0][nt] = __builtin_amdgcn_mfma_f32_16x16x32_bf16(af0, bf[nt], acc[0][nt], 0, 0, 0);
                acc[1][nt] = __builtin_amdgcn_mfma_f32_16x16x32_bf16(af1, bf[nt], acc[1][nt], 0, 0, 0);
            }
            bf[0] = Bs[kb * 128 + 4 * 16 + col];
            bf[1] = Bs[kb * 128 + 5 * 16 + col];
            acc[0][4] = __builtin_amdgcn_mfma_f32_16x16x32_bf16(af0, bf[0], acc[0][4], 0, 0, 0);
            acc[1][4] = __builtin_amdgcn_mfma_f32_16x16x32_bf16(af1, bf[0], acc[1][4], 0, 0, 0);
            acc[0][5] = __builtin_amdgcn_mfma_f32_16x16x32_bf16(af0, bf[1], acc[0][5], 0, 0, 0);
            acc[1][5] = __builtin_amdgcn_mfma_f32_16x16x32_bf16(af1, bf[1], acc[1][5], 0, 0, 0);
            if (ks == 2) {             // q-rpe cols only touch k>=64
                bf[2] = Bs[kb * 128 + 6 * 16 + col];
                bf[3] = Bs[kb * 128 + 7 * 16 + col];
                acc[0][6] = __builtin_amdgcn_mfma_f32_16x16x32_bf16(af0, bf[2], acc[0][6], 0, 0, 0);
                acc[1][6] = __builtin_amdgcn_mfma_f32_16x16x32_bf16(af1, bf[2], acc[1][6], 0, 0, 0);
                acc[0][7] = __builtin_amdgcn_mfma_f32_16x16x32_bf16(af0, bf[3], acc[0][7], 0, 0, 0);
                acc[1][7] = __builtin_amdgcn_mfma_f32_16x16x32_bf16(af1, bf[3], acc[1][7], 0, 0, 0);
            }
        }

        // ---- issue next tile's x/ea gather (lands during P4) ----
        int chn = vn ? cpn.x : 0;
        float4 xa[10]; float ear[9];
        if (half == 0) {
            const float4* xr = (const float4*)(xc + (size_t)chn * 64);
#pragma unroll
            for (int i = 0; i < 10; ++i) xa[i] = xr[i];
        } else {
            const float4* xr = (const float4*)(xc + (size_t)chn * 64);
#pragma unroll
            for (int i = 0; i < 6; ++i) xa[i] = xr[10 + i];
            const float* er = ea_g + (size_t)chn * 9;
#pragma unroll
            for (int r = 0; r < 9; ++r) ear[r] = er[r];
        }

        // ---- P4: in-reg compat (mt-sequential, reg-light) -> e_lds ----
#pragma unroll
        for (int mt = 0; mt < 2; ++mt) {
            float comp[4][2];
#pragma unroll
            for (int r = 0; r < 4; ++r) {
                int cc = wbase + mt * 16 + quad * 4 + r;
                int p = par_s[cc];
                p = (p < NPAR) ? p : 0;         // safe dummy for invalid
                const float* qpr = qp + (size_t)p * 32;
#pragma unroll
                for (int nt = 0; nt < 2; ++nt)
                    comp[r][nt] = acc[mt][nt][r] * (qpr[nt * 16 + col] + acc[mt][nt + 6][r]);
            }
#pragma unroll
            for (int m = 1; m < 8; m <<= 1)
#pragma unroll
                for (int r = 0; r < 4; ++r)
#pragma unroll
                    for (int nt = 0; nt < 2; ++nt)
                        comp[r][nt] += __shfl_xor(comp[r][nt], m, 64);
            // one store per lane: collo -> (rS, ntS); static select (no dyn idx)
            int collo = lane & 7, colhi = (lane >> 3) & 1;
            float eArg = comp[0][0];
            eArg = (collo == 1) ? comp[1][0] : eArg;
            eArg = (collo == 2) ? comp[2][0] : eArg;
            eArg = (collo == 3) ? comp[3][0] : eArg;
            eArg = (collo == 4) ? comp[0][1] : eArg;
            eArg = (collo == 5) ? comp[1][1] : eArg;
            eArg = (collo == 6) ? comp[2][1] : eArg;
            eArg = (collo == 7) ? comp[3][1] : eArg;
            int rS = collo & 3, ntS = collo >> 2;
            int cS = wbase + mt * 16 + quad * 4 + rS;
            float eV = (cS < validCB) ? __expf(eArg) : 0.f;
            e_lds[cS * 4 + ntS * 2 + colhi] = eV;   // 64 consecutive words: no conflict
        }

        // ---- pack prefetched tile (loads have landed under P4) ----
        if (half == 0) {
#pragma unroll
            for (int kb = 0; kb < 5; ++kb) {
                uint4 u;
                u.x = pack2bf(xa[kb*2].x,   xa[kb*2].y);
                u.y = pack2bf(xa[kb*2].z,   xa[kb*2].w);
                u.z = pack2bf(xa[kb*2+1].x, xa[kb*2+1].y);
                u.w = pack2bf(xa[kb*2+1].z, xa[kb*2+1].w);
                pk[kb] = vn ? u : make_uint4(0u,0u,0u,0u);
            }
        } else {
#pragma unroll
            for (int kb = 0; kb < 3; ++kb) {
                uint4 u;
                u.x = pack2bf(xa[kb*2].x,   xa[kb*2].y);
                u.y = pack2bf(xa[kb*2].z,   xa[kb*2].w);
                u.z = pack2bf(xa[kb*2+1].x, xa[kb*2+1].y);
                u.w = pack2bf(xa[kb*2+1].z, xa[kb*2+1].w);
                pk[kb] = vn ? u : make_uint4(0u,0u,0u,0u);
            }
            uint4 u8;
            u8.x = pack2bf(ear[0], ear[1]); u8.y = pack2bf(ear[2], ear[3]);
            u8.z = pack2bf(ear[4], ear[5]); u8.w = pack2bf(ear[6], ear[7]);
            pk[3] = vn ? u8 : make_uint4(0u,0u,0u,0u);
            uint4 u9;
            u9.x = pack2bf(ear[8], 1.f); u9.y = 0u; u9.z = 0u; u9.w = 0u;
            pk[4] = vn ? u9 : make_uint4(0u,0u,0u,0u);
        }
        cp.x = chn; cp.y = vn ? cpn.y : 0x7fffffff;

        // ---- segment heads ----
        {
            bool valid = (c == tid) && (tid < validCB);   // threads 128+ invalid
            bool vld = (tid < validCB);
            bool ishead = vld && (tid == 0 || par_s[tid - 1] != par_s[tid]);
            (void)valid;
            unsigned long long mask = __ballot(ishead);
            if (lane == 0) wcnt[wave] = __popcll(mask);
            __syncthreads();   // B2: e_lds + wcnt published; all waves past P2
            int base = 0;
#pragma unroll
            for (int w = 0; w < 4; ++w) if (w < wave) base += wcnt[w];
            if (ishead) segStart[base + __popcll(mask & ((1ull << lane) - 1))] = tid;
            if (tid == 0) {
                int ns = wcnt[0] + wcnt[1] + wcnt[2] + wcnt[3];
                segStart[ns] = validCB;
                segStart[129] = ns;
            }
        }

        // ---- P5: scale v frags by e -> wvS (overwrites A region) ----
#pragma unroll
        for (int mt = 0; mt < 2; ++mt) {
            int cb = wbase + mt * 16 + quad * 4;
#pragma unroll
            for (int nt = 2; nt < 6; ++nt) {
                int d = (nt - 2) * 16 + col;
                int h = nt - 2;
#pragma unroll
                for (int r = 0; r < 4; ++r) {
                    float e = e_lds[(cb + r) * 4 + h];
                    wvS[(cb + r) * 68 + d] = acc[mt][nt][r] * e;
                }
            }
        }
        __syncthreads();   // B3: wvS + segStart visible

        // ---- P6: segmented reduce. Wave per segment (lane = dim). ----
        {
            int nseg = segStart[129];
            for (int s = wave; s < nseg; s += 4) {
                int a = segStart[s], b = segStart[s + 1];
                int p = par_s[a];
                int d = lane, h = lane >> 4;
                float vs = 0.f, es = 0.f;
                for (int c2 = a; c2 < b; ++c2) {
                    vs += wvS[c2 * 68 + d];
                    es += e_lds[c2 * 4 + h];
                }
                bool full = (rowStart[p] == G + a) && (rowStart[p + 1] == G + b);
                if (full) {
                    outw[(size_t)p * 64 + d] = vs;
                    if ((d & 15) == 0) sW[(size_t)p * 4 + h] = es;
                } else {
                    atomicAdd(&outw[(size_t)p * 64 + d], vs);
                    if ((d & 15) == 0) atomicAdd(&sW[(size_t)p * 4 + h], es);
                }
            }
        }
        __syncthreads();   // B4: wvS consumed; A region free for next write
    }
}

// ---------------------------------------------------------------------------
// Kernel E: out[p][d] /= (s[p][d/16] + 1e-16)
// ---------------------------------------------------------------------------
__global__ __launch_bounds__(256) void norm_kernel(const float* __restrict__ sW,
                                                   float* __restrict__ out) {
    int t = blockIdx.x * 256 + threadIdx.x;
    if (t >= NPAR * 64) return;
    out[t] = out[t] / (sW[(t >> 6) * 4 + ((t >> 4) & 3)] + 1e-16f);
}

// ---------------------------------------------------------------------------
extern "C" void kernel_launch(void* const* d_in, const int* in_sizes, int n_in,
                              void* d_out, int out_size, void* d_ws, size_t ws_size,
                              hipStream_t stream) {
    const float* xc   = (const float*)d_in[0];
    const float* xp   = (const float*)d_in[1];
    const int*   idx  = (const int*)d_in[2];
    const float* ea   = (const float*)d_in[3];
    const float* wq   = (const float*)d_in[4];
    const float* bq   = (const float*)d_in[5];
    const float* wkv  = (const float*)d_in[6];
    const float* bkv  = (const float*)d_in[7];
    const float* wkr  = (const float*)d_in[8];
    const float* bkr  = (const float*)d_in[9];
    const float* wqr  = (const float*)d_in[10];
    const float* bqr  = (const float*)d_in[11];
    float* out = (float*)d_out;

    char* base = (char*)d_ws;
    size_t off = 0;
    auto alloc = [&](size_t bytes) {
        void* r = base + off;
        off += (bytes + 255) & ~(size_t)255;
        return r;
    };
    float* qp       = (float*)alloc((size_t)NPAR * 32 * sizeof(float));   // 12.8 MB
    int*   cnt      = (int*)  alloc((size_t)NPAR * sizeof(int));
    int*   rowStart = (int*)  alloc(((size_t)NPAR + 1) * sizeof(int));
    int*   cursor   = (int*)  alloc((size_t)NPAR * sizeof(int));
    int2*  ordCP    = (int2*) alloc((size_t)NC * sizeof(int2));           // 8 MB
    float* sW       = (float*)alloc((size_t)NPAR * 4 * sizeof(float));    // 1.6 MB
    int*   bsum     = (int*)  alloc((size_t)NBS * sizeof(int));
    uint4* Bg       = (uint4*)alloc((size_t)12 * 128 * sizeof(uint4));    // 24 KB
    (void)ws_size;

    hipMemsetAsync(cnt, 0, (size_t)NPAR * sizeof(int), stream);
    hipMemsetAsync(sW,  0, (size_t)NPAR * 4 * sizeof(float), stream);
    hipMemsetAsync(out, 0, (size_t)NPAR * 64 * sizeof(float), stream);

    qproj_kernel  <<<(NPAR + 255) / 256, 256, 0, stream>>>(xp, wq, bq, qp);
    prepB_kernel  <<<1,                  256, 0, stream>>>(wkv, bkv, wkr, bkr, wqr, bqr, Bg);
    hist_kernel   <<<(NC + 255) / 256,   256, 0, stream>>>(idx, cnt);
    scanA_kernel  <<<NBS,               1024, 0, stream>>>(cnt, bsum);
    scanB_kernel  <<<1,                  128, 0, stream>>>(bsum);
    scanC_kernel  <<<NBS,               1024, 0, stream>>>(cnt, bsum, rowStart, cursor);
    scatter_kernel<<<(NC + 255) / 256,   256, 0, stream>>>(idx, cursor, ordCP);
    fused_kernel  <<<GRID_F,             256, 0, stream>>>(xc, ea, ordCP, rowStart,
                                                           Bg, qp, out, sW);
    norm_kernel   <<<(NPAR * 64 + 255) / 256, 256, 0, stream>>>(sW, out);
}

// Round 6
// 655.483 us; speedup vs baseline: 1.5250x; 1.5250x over previous
//
#include <hip/hip_runtime.h>

#define NC    1000000
#define NPAR  100000
#define DIM   64
#define H     4
#define RPE   9
#define SCALE 0.35355339059327373f  // DQK^-0.5
#define CB    128                    // children per fused tile
#define NBS   ((NPAR + 1023) / 1024) // 98 scan blocks
#define NT_TILES ((NC + CB - 1) / CB)// 7813
#define GRIDP 512                    // persistent: 2 blocks/CU (77.4KB LDS each)

typedef __attribute__((ext_vector_type(8))) short short8;   // 8 bf16 (4 VGPRs)
typedef __attribute__((ext_vector_type(4))) float f32x4;    // MFMA C/D frag

__device__ inline unsigned short f2bf(float f) {
    unsigned int u = __float_as_uint(f);
    u += 0x7fff + ((u >> 16) & 1);          // round-to-nearest-even
    return (unsigned short)(u >> 16);
}
__device__ inline unsigned int pack2bf(float a, float b) {
    return (unsigned int)f2bf(a) | ((unsigned int)f2bf(b) << 16);
}

// direct global->LDS DMA, HW-verified width 16 ONLY (m97). dest = wave-uniform
// base + lane*16.
__device__ inline void gl_lds16(const float* g, void* l) {
    __builtin_amdgcn_global_load_lds(
        (const __attribute__((address_space(1))) unsigned int*)g,
        (__attribute__((address_space(3))) unsigned int*)l, 16, 0, 0);
}

// ---------------------------------------------------------------------------
// Kernel A: qp[p][o] = SCALE*(x_parent[p].wq[:,o] + bq[o]). Thread per parent.
// ---------------------------------------------------------------------------
__global__ __launch_bounds__(256) void qproj_kernel(const float* __restrict__ xp,
                             const float* __restrict__ wq,
                             const float* __restrict__ bq,
                             float* __restrict__ qp) {
    __shared__ float wqT[32 * 64];   // wqT[o*64+j] = wq[j*32+o]
    __shared__ float bqL[32];
    int tid = threadIdx.x;
    for (int i = tid; i < 2048; i += 256) { int o = i >> 6, j = i & 63; wqT[i] = wq[j * 32 + o]; }
    if (tid < 32) bqL[tid] = bq[tid];
    __syncthreads();
    int p = blockIdx.x * 256 + tid;
    if (p >= NPAR) return;
    float4 x4[16];
    const float4* xr = (const float4*)(xp + (size_t)p * 64);
#pragma unroll
    for (int i = 0; i < 16; ++i) x4[i] = xr[i];
    float* qpr = qp + (size_t)p * 32;
#pragma unroll 1
    for (int o = 0; o < 32; ++o) {
        float acc = bqL[o];
        const float4* w4 = (const float4*)(wqT + o * 64);
#pragma unroll
        for (int j = 0; j < 16; ++j) { float4 w = w4[j], xx = x4[j];
            acc += xx.x * w.x + xx.y * w.y + xx.z * w.z + xx.w * w.w; }
        qpr[o] = acc * SCALE;
    }
}

// ---------------------------------------------------------------------------
// Kernel P: pre-pack B (96x128 bf16 GEMM operand) into global, once.
// ---------------------------------------------------------------------------
__global__ __launch_bounds__(256) void prepB_kernel(
    const float* __restrict__ wkv, const float* __restrict__ bkv,
    const float* __restrict__ wkr, const float* __restrict__ bkr,
    const float* __restrict__ wqr, const float* __restrict__ bqr,
    uint4* __restrict__ Bg) {
    int tid = threadIdx.x;
    for (int i = tid; i < 12 * 128; i += 256) {
        int kb = i >> 7, n = i & 127;
        float w[8];
#pragma unroll
        for (int jj = 0; jj < 8; ++jj) {
            int k = kb * 8 + jj;
            float val = 0.f;
            if (n < 32) {                       // k-projection (x + rpe + bias)
                if (k < 64)       val = wkv[k * 96 + n];
                else if (k < 73)  val = wkr[(k - 64) * 32 + n];
                else if (k == 73) val = bkv[n] + bkr[n];
            } else if (n < 96) {                // v-projection
                int d = n - 32;
                if (k < 64)       val = wkv[k * 96 + 32 + d];
                else if (k == 73) val = bkv[32 + d];
            } else {                            // q rpe (+bias)
                int o = n - 96;
                if (k >= 64 && k < 73) val = wqr[(k - 64) * 32 + o];
                else if (k == 73)      val = bqr[o];
            }
            w[jj] = val;
        }
        uint4 v;
        v.x = pack2bf(w[0], w[1]); v.y = pack2bf(w[2], w[3]);
        v.z = pack2bf(w[4], w[5]); v.w = pack2bf(w[6], w[7]);
        Bg[kb * 128 + n] = v;
    }
}

// ---------------------------------------------------------------------------
// Kernel B1: per-parent child histogram (1M int atomics).
// ---------------------------------------------------------------------------
__global__ __launch_bounds__(256) void hist_kernel(const int* __restrict__ index,
                            int* __restrict__ cnt) {
    int c = blockIdx.x * 256 + threadIdx.x;
    if (c >= NC) return;
    atomicAdd(&cnt[index[c]], 1);
}

// ---------------------------------------------------------------------------
// Scan phase A: per-block sums of cnt (98 blocks x 1024 threads).
// ---------------------------------------------------------------------------
__global__ __launch_bounds__(1024) void scanA_kernel(const int* __restrict__ cnt,
                                                     int* __restrict__ bsum) {
    __shared__ int red[16];
    int i = blockIdx.x * 1024 + threadIdx.x;
    int v = (i < NPAR) ? cnt[i] : 0;
#pragma unroll
    for (int off = 32; off; off >>= 1) v += __shfl_down(v, off, 64);
    if ((threadIdx.x & 63) == 0) red[threadIdx.x >> 6] = v;
    __syncthreads();
    if (threadIdx.x < 16) {
        int s = red[threadIdx.x];
#pragma unroll
        for (int off = 8; off; off >>= 1) s += __shfl_down(s, off, 16);
        if (threadIdx.x == 0) bsum[blockIdx.x] = s;
    }
}

// ---------------------------------------------------------------------------
// Scan phase B: exclusive scan of the 98 block sums (1 tiny block).
// ---------------------------------------------------------------------------
__global__ __launch_bounds__(128) void scanB_kernel(int* __restrict__ bsum) {
    __shared__ int s[128];
    int t = threadIdx.x;
    int v = (t < NBS) ? bsum[t] : 0;
    s[t] = v;
    __syncthreads();
    for (int off = 1; off < 128; off <<= 1) {
        int x = s[t];
        int add = (t >= off) ? s[t - off] : 0;
        __syncthreads();
        s[t] = x + add;
        __syncthreads();
    }
    if (t < NBS) bsum[t] = s[t] - v;    // inclusive -> exclusive
}

// ---------------------------------------------------------------------------
// Scan phase C: block-local exclusive scan + block offset -> rowStart, cursor.
// ---------------------------------------------------------------------------
__global__ __launch_bounds__(1024) void scanC_kernel(const int* __restrict__ cnt,
                                                     const int* __restrict__ bsum,
                                                     int* __restrict__ rowStart,
                                                     int* __restrict__ cursor) {
    __shared__ int s[1024];
    int t = threadIdx.x;
    int i = blockIdx.x * 1024 + t;
    int v = (i < NPAR) ? cnt[i] : 0;
    s[t] = v;
    __syncthreads();
    for (int off = 1; off < 1024; off <<= 1) {
        int x = s[t];
        int add = (t >= off) ? s[t - off] : 0;
        __syncthreads();
        s[t] = x + add;
        __syncthreads();
    }
    int excl = s[t] - v + bsum[blockIdx.x];
    if (i < NPAR) { rowStart[i] = excl; cursor[i] = excl; }
    if (i == NPAR - 1) rowStart[NPAR] = excl + v;
}

// ---------------------------------------------------------------------------
// Kernel B3: scatter via cursor atomics: ordCP[cursor[p]++] = (c, p)
// ---------------------------------------------------------------------------
__global__ __launch_bounds__(256) void scatter_kernel(const int* __restrict__ index,
                               int* __restrict__ cursor,
                               int2* __restrict__ ordCP) {
    int c = blockIdx.x * 256 + threadIdx.x;
    if (c >= NC) return;
    int p = index[c];
    int pos = atomicAdd(&cursor[p], 1);
    ordCP[pos] = make_int2(c, p);
}

// ---------------------------------------------------------------------------
// Kernel C: MFMA fused pass. Persistent (512 blocks, 2/CU). X staged via
//  global_load_lds width=16 (verified) with source-side inverse XOR swizzle;
//  EA staged via registers (scalar loads early, ds_write after B3) — NO
//  unverified gl_lds widths. Next-tile staging overlaps current-tile compute.
// ---------------------------------------------------------------------------
__global__ __launch_bounds__(256, 2) void fused_kernel(
    const float* __restrict__ xc, const float* __restrict__ ea_g,
    const int2* __restrict__ ordCP,
    const int* __restrict__ rowStart,
    const uint4* __restrict__ Bg,
    const float* __restrict__ qp,
    float* __restrict__ outw, float* __restrict__ sW)
{
    __shared__ __align__(16) char LB[77344];
    float* Xc    = (float*)LB;               // [128][64] f32, chunk-swizzled
    float* EAc   = (float*)(LB + 32768);     // [128][12] f32 (9 used)
    float* wvS   = (float*)(LB + 38912);     // [128][68] f32 e-scaled v
    float* e_lds = (float*)(LB + 73728);     // [128][4]
    int*   par_s = (int*)  (LB + 75776);     // [2][128]
    int*   segSt = (int*)  (LB + 76800);     // [130]
    int*   wcnt  = (int*)  (LB + 77320);     // [4]

    const int tid  = threadIdx.x;
    const int lane = tid & 63, wave = tid >> 6;
    const int col  = lane & 15, quad = lane >> 4;
    const int wbase = wave * 32;
    const int wuni  = tid & ~63;             // wave-uniform thread base
    const int c     = tid & 127;
    const int half  = tid >> 7;
    const short8 zero8 = {0, 0, 0, 0, 0, 0, 0, 0};

    int ordV[8]; int2 cpS;
    float eaR0, eaR1, eaR2, eaR3, eaR4;

    // read next tile's ord data + issue EA scalar loads into registers
    auto readStage = [&](int Gn) {
#pragma unroll
        for (int it = 0; it < 8; ++it) {
            int row = (it * 256 + tid) >> 4;
            ordV[it] = ordCP[min(Gn + row, NC - 1)].x;
        }
        int g2 = Gn + c;
        int2 cp = ordCP[min(g2, NC - 1)];
        if (g2 >= NC) cp.y = 0x7fffffff;
        cpS = cp;
        const float* e = ea_g + (size_t)cp.x * 9 + half * 5;
        eaR0 = e[0]; eaR1 = e[1]; eaR2 = e[2]; eaR3 = e[3];
        eaR4 = (half == 0) ? e[4] : 0.f;     // half1 never reads slot 4 (OOB guard)
    };
    // issue X global->LDS (linear dest, inverse-swizzled per-lane source)
    auto stageX = [&]() {
#pragma unroll
        for (int it = 0; it < 8; ++it) {
            int cid = it * 256 + tid;
            int row = cid >> 4, sub = cid & 15;
            int subs = sub ^ ((row & 7) << 1);          // inverse swizzle on source
            const float* src = xc + (size_t)ordV[it] * 64 + subs * 4;
            gl_lds16(src, (char*)Xc + it * 4096 + wuni * 16);
        }
    };
    // commit EA registers -> LDS (half0: floats 0..4, half1: floats 5..8)
    auto writeEA = [&]() {
        float* d = EAc + c * 12 + half * 5;
        d[0] = eaR0; d[1] = eaR1; d[2] = eaR2; d[3] = eaR3;
        if (half == 0) d[4] = eaR4;
    };

    // ---- prologue: stage tile t0 ----
    const int t0 = blockIdx.x;
    readStage(t0 * CB);
    stageX();
    if (tid < CB) par_s[tid] = cpS.y;        // slot 0
    writeEA();

    int iter = 0;
    for (int t = t0; t < NT_TILES; t += GRIDP, ++iter) {
        const int cur = iter & 1, nxt = cur ^ 1;
        const int G = t * CB;
        const int validCB = min(NC - G, CB);
        const bool hn = (t + GRIDP) < NT_TILES;

        __syncthreads();   // B0: staged tile t fully landed + LDS writes visible

        if (hn) readStage((t + GRIDP) * CB);  // vmem loads overlap the ds_reads below

        // ---- fragment ds_reads (f32) — must precede B_Aread ----
        float xfrag[2][3][8];
#pragma unroll
        for (int ks = 0; ks < 3; ++ks) {
            int kb = ks * 4 + quad;
#pragma unroll
            for (int mh = 0; mh < 2; ++mh) {
                int r = wbase + mh * 16 + col;
                float4 fa, fb;
                if (kb < 8) {
                    int sub = (kb * 2) ^ ((r & 7) << 1);    // swizzled read
                    const float* pa = Xc + r * 64 + sub * 4;
                    fa = *(const float4*)pa; fb = *(const float4*)(pa + 4);
                } else if (kb == 8) {
                    const float* pa = EAc + r * 12;
                    fa = *(const float4*)pa; fb = *(const float4*)(pa + 4);
                } else if (kb == 9) {
                    const float* pa = EAc + r * 12 + 8;
                    fa = *(const float4*)pa; fb = make_float4(0.f, 0.f, 0.f, 0.f);
                } else {
                    fa = make_float4(0.f, 0.f, 0.f, 0.f); fb = fa;
                }
                xfrag[mh][ks][0] = fa.x; xfrag[mh][ks][1] = fa.y;
                xfrag[mh][ks][2] = fa.z; xfrag[mh][ks][3] = fa.w;
                xfrag[mh][ks][4] = fb.x; xfrag[mh][ks][5] = fb.y;
                xfrag[mh][ks][6] = fb.z; xfrag[mh][ks][7] = fb.w;
            }
        }
        __syncthreads();   // B_Aread: all waves done reading Xc/EAc

        // ---- issue next tile's X staging (overlaps MFMA + compat) ----
        if (hn) {
            if (tid < CB) par_s[nxt * CB + tid] = cpS.y;
            stageX();
        }

        // ---- pack frags to bf16 ----
        short8 af[2][3];
#pragma unroll
        for (int ks = 0; ks < 3; ++ks) {
            int kb = ks * 4 + quad;
#pragma unroll
            for (int mh = 0; mh < 2; ++mh) {
                short8 a = zero8;
                if (kb < 9) {
#pragma unroll
                    for (int j = 0; j < 8; ++j) a[j] = (short)f2bf(xfrag[mh][ks][j]);
                } else if (kb == 9) {
                    a[0] = (short)f2bf(xfrag[mh][ks][0]);
                    a[1] = (short)0x3F80;           // bias row: 1.0 bf16
                }
                af[mh][ks] = a;
            }
        }

        // ---- P2: MFMA. Wave computes 32 children x 128 outputs ----
        f32x4 acc[2][8];
#pragma unroll
        for (int mt = 0; mt < 2; ++mt)
#pragma unroll
            for (int nt = 0; nt < 8; ++nt) acc[mt][nt] = (f32x4){0.f, 0.f, 0.f, 0.f};
        const short8* Bs = (const short8*)Bg;
#pragma unroll
        for (int ks = 0; ks < 3; ++ks) {
            const int kb = ks * 4 + quad;
            short8 af0 = af[0][ks], af1 = af[1][ks];
            short8 bf[4];
#pragma unroll
            for (int nt = 0; nt < 4; ++nt) bf[nt] = Bs[kb * 128 + nt * 16 + col];
#pragma unroll
            for (int nt = 0; nt < 4; ++nt) {
                acc[0][nt] = __builtin_amdgcn_mfma_f32_16x16x32_bf16(af0, bf[nt], acc[0][nt], 0, 0, 0);
                acc[1][nt] = __builtin_amdgcn_mfma_f32_16x16x32_bf16(af1, bf[nt], acc[1][nt], 0, 0, 0);
            }
            bf[0] = Bs[kb * 128 + 4 * 16 + col];
            bf[1] = Bs[kb * 128 + 5 * 16 + col];
            acc[0][4] = __builtin_amdgcn_mfma_f32_16x16x32_bf16(af0, bf[0], acc[0][4], 0, 0, 0);
            acc[1][4] = __builtin_amdgcn_mfma_f32_16x16x32_bf16(af1, bf[0], acc[1][4], 0, 0, 0);
            acc[0][5] = __builtin_amdgcn_mfma_f32_16x16x32_bf16(af0, bf[1], acc[0][5], 0, 0, 0);
            acc[1][5] = __builtin_amdgcn_mfma_f32_16x16x32_bf16(af1, bf[1], acc[1][5], 0, 0, 0);
            if (ks == 2) {             // q-rpe cols only touch k>=64
                bf[2] = Bs[kb * 128 + 6 * 16 + col];
                bf[3] = Bs[kb * 128 + 7 * 16 + col];
                acc[0][6] = __builtin_amdgcn_mfma_f32_16x16x32_bf16(af0, bf[2], acc[0][6], 0, 0, 0);
                acc[1][6] = __builtin_amdgcn_mfma_f32_16x16x32_bf16(af1, bf[2], acc[1][6], 0, 0, 0);
                acc[0][7] = __builtin_amdgcn_mfma_f32_16x16x32_bf16(af0, bf[3], acc[0][7], 0, 0, 0);
                acc[1][7] = __builtin_amdgcn_mfma_f32_16x16x32_bf16(af1, bf[3], acc[1][7], 0, 0, 0);
            }
        }

        // ---- P4: in-reg compat (mt-sequential) -> e_lds ----
#pragma unroll
        for (int mt = 0; mt < 2; ++mt) {
            float comp[4][2];
#pragma unroll
            for (int r = 0; r < 4; ++r) {
                int cc = wbase + mt * 16 + quad * 4 + r;
                int p = par_s[cur * CB + cc];
                p = (p < NPAR) ? p : 0;         // safe dummy for invalid
                const float* qpr = qp + (size_t)p * 32;
#pragma unroll
                for (int nt = 0; nt < 2; ++nt)
                    comp[r][nt] = acc[mt][nt][r] * (qpr[nt * 16 + col] + acc[mt][nt + 6][r]);
            }
#pragma unroll
            for (int m = 1; m < 8; m <<= 1)
#pragma unroll
                for (int r = 0; r < 4; ++r)
#pragma unroll
                    for (int nt = 0; nt < 2; ++nt)
                        comp[r][nt] += __shfl_xor(comp[r][nt], m, 64);
            int collo = lane & 7, colhi = (lane >> 3) & 1;
            float eArg = comp[0][0];
            eArg = (collo == 1) ? comp[1][0] : eArg;
            eArg = (collo == 2) ? comp[2][0] : eArg;
            eArg = (collo == 3) ? comp[3][0] : eArg;
            eArg = (collo == 4) ? comp[0][1] : eArg;
            eArg = (collo == 5) ? comp[1][1] : eArg;
            eArg = (collo == 6) ? comp[2][1] : eArg;
            eArg = (collo == 7) ? comp[3][1] : eArg;
            int rS = collo & 3, ntS = collo >> 2;
            int cS = wbase + mt * 16 + quad * 4 + rS;
            float eV = (cS < validCB) ? __expf(eArg) : 0.f;
            e_lds[cS * 4 + ntS * 2 + colhi] = eV;   // 64 consecutive words/wave
        }

        // ---- segment heads ----
        {
            bool vld = (tid < validCB);
            bool ishead = vld && (tid == 0 || par_s[cur * CB + tid - 1] != par_s[cur * CB + tid]);
            unsigned long long mask = __ballot(ishead);
            if (lane == 0) wcnt[wave] = __popcll(mask);
            __syncthreads();   // B2: e_lds + wcnt published (drains staging vm)
            int base2 = 0;
#pragma unroll
            for (int w = 0; w < 4; ++w) if (w < wave) base2 += wcnt[w];
            if (ishead) segSt[base2 + __popcll(mask & ((1ull << lane) - 1))] = tid;
            if (tid == 0) {
                int ns = wcnt[0] + wcnt[1] + wcnt[2] + wcnt[3];
                segSt[ns] = validCB;
                segSt[129] = ns;
            }
        }

        // ---- P5: scale v frags by e -> wvS ----
#pragma unroll
        for (int mt = 0; mt < 2; ++mt) {
            int cb = wbase + mt * 16 + quad * 4;
#pragma unroll
            for (int nt = 2; nt < 6; ++nt) {
                int d = (nt - 2) * 16 + col;
                int h = nt - 2;
#pragma unroll
                for (int r = 0; r < 4; ++r) {
                    float e = e_lds[(cb + r) * 4 + h];
                    wvS[(cb + r) * 68 + d] = acc[mt][nt][r] * e;
                }
            }
        }
        __syncthreads();   // B3: wvS + segStart visible

        // ---- commit next tile's EA regs -> LDS (EAc free since B_Aread) ----
        if (hn) writeEA();

        // ---- P6: segmented reduce. Wave per segment (lane = dim). ----
        {
            int nseg = segSt[129];
            for (int s = wave; s < nseg; s += 4) {
                int a = segSt[s], b = segSt[s + 1];
                int p = par_s[cur * CB + a];
                int d = lane, h = lane >> 4;
                float vs = 0.f, es = 0.f;
                for (int c2 = a; c2 < b; ++c2) {
                    vs += wvS[c2 * 68 + d];
                    es += e_lds[c2 * 4 + h];
                }
                bool full = (rowStart[p] == G + a) && (rowStart[p + 1] == G + b);
                if (full) {
                    outw[(size_t)p * 64 + d] = vs;
                    if ((d & 15) == 0) sW[(size_t)p * 4 + h] = es;
                } else {
                    atomicAdd(&outw[(size_t)p * 64 + d], vs);
                    if ((d & 15) == 0) atomicAdd(&sW[(size_t)p * 4 + h], es);
                }
            }
        }
        // next iter's B0 separates P6 reads from next tile's frag reads
    }
}

// ---------------------------------------------------------------------------
// Kernel E: out[p][d] /= (s[p][d/16] + 1e-16)
// ---------------------------------------------------------------------------
__global__ __launch_bounds__(256) void norm_kernel(const float* __restrict__ sW,
                                                   float* __restrict__ out) {
    int t = blockIdx.x * 256 + threadIdx.x;
    if (t >= NPAR * 64) return;
    out[t] = out[t] / (sW[(t >> 6) * 4 + ((t >> 4) & 3)] + 1e-16f);
}

// ---------------------------------------------------------------------------
extern "C" void kernel_launch(void* const* d_in, const int* in_sizes, int n_in,
                              void* d_out, int out_size, void* d_ws, size_t ws_size,
                              hipStream_t stream) {
    const float* xc   = (const float*)d_in[0];
    const float* xp   = (const float*)d_in[1];
    const int*   idx  = (const int*)d_in[2];
    const float* ea   = (const float*)d_in[3];
    const float* wq   = (const float*)d_in[4];
    const float* bq   = (const float*)d_in[5];
    const float* wkv  = (const float*)d_in[6];
    const float* bkv  = (const float*)d_in[7];
    const float* wkr  = (const float*)d_in[8];
    const float* bkr  = (const float*)d_in[9];
    const float* wqr  = (const float*)d_in[10];
    const float* bqr  = (const float*)d_in[11];
    float* out = (float*)d_out;

    char* base = (char*)d_ws;
    size_t off = 0;
    auto alloc = [&](size_t bytes) {
        void* r = base + off;
        off += (bytes + 255) & ~(size_t)255;
        return r;
    };
    float* qp       = (float*)alloc((size_t)NPAR * 32 * sizeof(float));   // 12.8 MB
    int*   cnt      = (int*)  alloc((size_t)NPAR * sizeof(int));
    int*   rowStart = (int*)  alloc(((size_t)NPAR + 1) * sizeof(int));
    int*   cursor   = (int*)  alloc((size_t)NPAR * sizeof(int));
    int2*  ordCP    = (int2*) alloc((size_t)NC * sizeof(int2));           // 8 MB
    float* sW       = (float*)alloc((size_t)NPAR * 4 * sizeof(float));    // 1.6 MB
    int*   bsum     = (int*)  alloc((size_t)NBS * sizeof(int));
    uint4* Bg       = (uint4*)alloc((size_t)12 * 128 * sizeof(uint4));    // 24 KB
    (void)ws_size;

    hipMemsetAsync(cnt, 0, (size_t)NPAR * sizeof(int), stream);
    hipMemsetAsync(sW,  0, (size_t)NPAR * 4 * sizeof(float), stream);
    hipMemsetAsync(out, 0, (size_t)NPAR * 64 * sizeof(float), stream);

    qproj_kernel  <<<(NPAR + 255) / 256, 256, 0, stream>>>(xp, wq, bq, qp);
    prepB_kernel  <<<1,                  256, 0, stream>>>(wkv, bkv, wkr, bkr, wqr, bqr, Bg);
    hist_kernel   <<<(NC + 255) / 256,   256, 0, stream>>>(idx, cnt);
    scanA_kernel  <<<NBS,               1024, 0, stream>>>(cnt, bsum);
    scanB_kernel  <<<1,                  128, 0, stream>>>(bsum);
    scanC_kernel  <<<NBS,               1024, 0, stream>>>(cnt, bsum, rowStart, cursor);
    scatter_kernel<<<(NC + 255) / 256,   256, 0, stream>>>(idx, cursor, ordCP);
    fused_kernel  <<<GRIDP,              256, 0, stream>>>(xc, ea, ordCP, rowStart,
                                                           Bg, qp, out, sW);
    norm_kernel   <<<(NPAR * 64 + 255) / 256, 256, 0, stream>>>(sW, out);
}